// Round 17
// baseline (117.225 us; speedup 1.0000x reference)
//
#include <hip/hip_runtime.h>
#include <hip/hip_bf16.h>
#include <math.h>
#include <string.h>

// Problem: B=64, R=20, L=1024, D=2048 fp32.  out[b,l] = max_r <region[b,r,:], word[b,l,:]>
// Memory-bound: 548 MB mandatory -> ~84-98us @ measured achievable BW.
//
// Round-17 = round-16 with the nontemporal compile error fixed: builtin wants
// scalar/ext-vector pointer types, not HIP_vector_type float4 -> load as
// ext_vector f32x4 (same global_load_dwordx4 + nt policy bit).
//  - Theory under test (unchanged): the 537 MB word stream (zero reuse)
//    LRU-evicts the 1.25 MB/XCD region set from L2, so each block's 160 KB
//    restage (82 MB total) misses to L3/HBM. NT word loads = evict-first ->
//    regions stay L2-resident.
//  - Everything else identical to round 15 (110.7us best): MFMA, regions
//    staged once as bf16 A-fragments in 80 KB LDS (ONE barrier), words 2-deep
//    ping-pong in named regs, cvt_pk conversion, peeled tail, pre-issued
//    first loads.
#define NREG   20
#define LWORDS 1024
#define DDIM   2048
#define TPB    512
#define KSTEPS (DDIM / 32)          // 64 MFMA K-steps

typedef __attribute__((ext_vector_type(8))) short bf16x8;
typedef __attribute__((ext_vector_type(4))) float f32x4;
typedef __attribute__((ext_vector_type(4))) unsigned int u32x4;

// pack 2 fp32 -> 2 bf16 (RNE) -> one u32; compiler emits v_cvt_pk_bf16_f32
__device__ __forceinline__ unsigned pk2(float lo, float hi) {
    __hip_bfloat162 h = __float22bfloat162_rn(make_float2(lo, hi));
    unsigned u;
    memcpy(&u, &h, 4);
    return u;
}

// p0,p1 are f32x4 (ext-vector, [] indexed)
#define CVT8(bq, p0, p1)                                                       \
    do {                                                                       \
        u32x4 t_;                                                              \
        t_[0] = pk2(p0[0], p0[1]); t_[1] = pk2(p0[2], p0[3]);                  \
        t_[2] = pk2(p1[0], p1[1]); t_[3] = pk2(p1[2], p1[3]);                  \
        memcpy(&bq, &t_, 16);                                                  \
    } while (0)

// unguarded: callers guarantee kk < KSTEPS.  NON-TEMPORAL: words have zero
// reuse; evict-first policy keeps the region working set in L2.
#define WLOAD(va, vb, kk)                                                      \
    do {                                                                       \
        const f32x4* p_ = reinterpret_cast<const f32x4*>(                      \
            wbase + (size_t)(kk) * 32);                                        \
        va = __builtin_nontemporal_load(p_);                                   \
        vb = __builtin_nontemporal_load(p_ + 1);                               \
    } while (0)

// one MFMA K-step: cvt word regs -> bf16, read A-fragments, 2 MFMAs
#define CSTEP(kk, va, vb)                                                      \
    do {                                                                       \
        bf16x8 bq_; CVT8(bq_, va, vb);                                         \
        const bf16x8 a0_ = lds0[(kk) * 64 + lane];                             \
        const bf16x8 a1_ = lds1[(kk) * 16 + (col & 3) * 4 + kg];               \
        acc0 = __builtin_amdgcn_mfma_f32_16x16x32_bf16(a0_, bq_, acc0, 0, 0, 0); \
        acc1 = __builtin_amdgcn_mfma_f32_16x16x32_bf16(a1_, bq_, acc1, 0, 0, 0); \
    } while (0)

__global__ __launch_bounds__(TPB)
void score_mfma_kernel(const float* __restrict__ in0,   // (B*20, D) regions
                       const float* __restrict__ in1,   // (B, L, D) words
                       float* __restrict__ out) {       // (B, 1, L)
    // A-fragments, lane-sequential 16B reads (conflict-free):
    //  lds0[ks*64 + lane]          : rows 0-15,  row=lane&15, k=ks*32+(lane>>4)*8
    //  lds1[ks*16 + (row&3)*4 + kg]: rows 16-19 compact (4-lane broadcast read)
    __shared__ bf16x8 lds0[KSTEPS * 64];   // 64 KB
    __shared__ bf16x8 lds1[KSTEPS * 16];   // 16 KB

    const int bid  = blockIdx.x;
    const int b    = bid & 63;              // batch -> XCD b%8
    const int tb   = bid >> 6;              // word slab 0..7 (128 words each)
    const int tid  = threadIdx.x;
    const int wave = tid >> 6;
    const int lane = tid & 63;
    const int col  = lane & 15;             // word column within 16-word tile
    const int kg   = lane >> 4;             // k-group 0..3 (8 k each)

    const float* reg0 = in0 + (size_t)b * NREG * DDIM;
    const float* wbase = in1
        + ((size_t)b * LWORDS + tb * 128 + wave * 16 + col) * DDIM + kg * 8;

    // pre-issue the first two word prefetches: word stream starts at t=0,
    // overlapping the staging phase below.
    f32x4 pa0, pa1, pb0, pb1;
    WLOAD(pa0, pa1, 0);
    WLOAD(pb0, pb1, 1);

    // ---- stage regions once: fp32 -> bf16 -> fragment-ordered LDS ----
    #pragma unroll
    for (int i = 0; i < 8; ++i) {           // rows 0-15: 4096 slots
        const int S = i * TPB + tid;
        const int ks = S >> 6, l = S & 63, r = l & 15, g = l >> 4;
        const float* src = reg0 + (size_t)r * DDIM + ks * 32 + g * 8;
        const f32x4 x = *reinterpret_cast<const f32x4*>(src);
        const f32x4 y = *reinterpret_cast<const f32x4*>(src + 4);
        bf16x8 o; CVT8(o, x, y);
        lds0[S] = o;
    }
    #pragma unroll
    for (int i = 0; i < 2; ++i) {           // rows 16-19: 1024 slots
        const int S = i * TPB + tid;
        const int ks = S >> 4, r4 = (S >> 2) & 3, g = S & 3;
        const float* src = reg0 + (size_t)(16 + r4) * DDIM + ks * 32 + g * 8;
        const f32x4 x = *reinterpret_cast<const f32x4*>(src);
        const f32x4 y = *reinterpret_cast<const f32x4*>(src + 4);
        bf16x8 o; CVT8(o, x, y);
        lds1[S] = o;
    }
    __syncthreads();   // the ONLY barrier in the kernel

    f32x4 acc0 = {0.f, 0.f, 0.f, 0.f};      // rows 0-15
    f32x4 acc1 = {0.f, 0.f, 0.f, 0.f};      // rows 16-19 (x4 duplicated)

    for (int ks = 0; ks < KSTEPS - 2; ks += 2) {
        CSTEP(ks,     pa0, pa1);  WLOAD(pa0, pa1, ks + 2);
        CSTEP(ks + 1, pb0, pb1);  WLOAD(pb0, pb1, ks + 3);
    }
    CSTEP(KSTEPS - 2, pa0, pa1);            // peeled tail: no loads, no guards
    CSTEP(KSTEPS - 1, pb0, pb1);

    // ---- max over regions ----
    // D layout (m89-verified): col = lane&15, row = (lane>>4)*4 + reg.
    float m = fmaxf(fmaxf(fmaxf(acc0[0], acc0[1]), fmaxf(acc0[2], acc0[3])),
                    fmaxf(fmaxf(acc1[0], acc1[1]), fmaxf(acc1[2], acc1[3])));
    m = fmaxf(m, __shfl_xor(m, 16, 64));
    m = fmaxf(m, __shfl_xor(m, 32, 64));
    if (lane < 16)
        out[(size_t)b * LWORDS + tb * 128 + wave * 16 + col] = m;
}

extern "C" void kernel_launch(void* const* d_in, const int* in_sizes, int n_in,
                              void* d_out, int out_size, void* d_ws, size_t ws_size,
                              hipStream_t stream) {
    const float* in0 = (const float*)d_in[0];   // (B*20, D)
    const float* in1 = (const float*)d_in[1];   // (B, L, D)
    float* out = (float*)d_out;                  // (B, 1, L)

    const int grid = 64 * (LWORDS / 128);        // 512 blocks, 2/CU (80KB LDS)
    score_mfma_kernel<<<grid, TPB, 0, stream>>>(in0, in1, out);
}

// Round 18
// 112.202 us; speedup vs baseline: 1.0448x; 1.0448x over previous
//
#include <hip/hip_runtime.h>
#include <hip/hip_bf16.h>
#include <math.h>
#include <string.h>

// Problem: B=64, R=20, L=1024, D=2048 fp32.  out[b,l] = max_r <region[b,r,:], word[b,l,:]>
// Memory-bound: 548 MB mandatory -> ~84-98us @ measured achievable BW.
//
// Round-18 = round-15 (110.7us best) + REGION PREPASS to bf16 fragments in d_ws.
//  - round-17 falsified the NT/eviction theory (NT hurt: 117us). Reverted.
//  - prepass kernel converts regions fp32->bf16 ONCE, in exact LDS-fragment
//    order (5.24 MB total). Main kernel stages 80KB/block via 10 async
//    global_load_lds per thread-issue: stage bytes halved (82->41 MB, mostly
//    L2-resident 640KB/XCD set), stage VALU eliminated, staging fully async
//    behind the pre-issued word loads. ONE barrier, then barrier-free loop.
//  - main loop identical to round 15: 2-deep named-reg word ping-pong,
//    cvt_pk conversion, peeled tail, M=20 = 16 + 4x-replicated-4.
//  - fallback (ws too small): round-15 kernel verbatim.
#define NREG   20
#define LWORDS 1024
#define DDIM   2048
#define TPB    512
#define KSTEPS (DDIM / 32)          // 64 MFMA K-steps
#define FRAGS  (KSTEPS * 64 + KSTEPS * 16)   // 5120 fragments/batch (16B each)

typedef __attribute__((ext_vector_type(8))) short bf16x8;
typedef __attribute__((ext_vector_type(4))) float f32x4;
typedef __attribute__((ext_vector_type(4))) unsigned int u32x4;

// async global->LDS, 16B per lane; dst wave-uniform, src per-lane
__device__ __forceinline__ void gload_lds16(const void* src, void* dst) {
    __builtin_amdgcn_global_load_lds(
        (const __attribute__((address_space(1))) void*)src,
        (__attribute__((address_space(3))) void*)dst,
        16, 0, 0);
}

// pack 2 fp32 -> 2 bf16 (RNE) -> one u32; compiler emits v_cvt_pk_bf16_f32
__device__ __forceinline__ unsigned pk2(float lo, float hi) {
    __hip_bfloat162 h = __float22bfloat162_rn(make_float2(lo, hi));
    unsigned u;
    memcpy(&u, &h, 4);
    return u;
}

#define CVT8(bq, p0, p1)                                                       \
    do {                                                                       \
        u32x4 t_;                                                              \
        t_[0] = pk2(p0[0], p0[1]); t_[1] = pk2(p0[2], p0[3]);                  \
        t_[2] = pk2(p1[0], p1[1]); t_[3] = pk2(p1[2], p1[3]);                  \
        memcpy(&bq, &t_, 16);                                                  \
    } while (0)

// plain (cached) word loads; unguarded: callers guarantee kk < KSTEPS
#define WLOAD(va, vb, kk)                                                      \
    do {                                                                       \
        const f32x4* p_ = reinterpret_cast<const f32x4*>(                      \
            wbase + (size_t)(kk) * 32);                                        \
        va = *p_;                                                              \
        vb = *(p_ + 1);                                                        \
    } while (0)

#define CSTEP(kk, va, vb)                                                      \
    do {                                                                       \
        bf16x8 bq_; CVT8(bq_, va, vb);                                         \
        const bf16x8 a0_ = lds0[(kk) * 64 + lane];                             \
        const bf16x8 a1_ = lds1[(kk) * 16 + (col & 3) * 4 + kg];               \
        acc0 = __builtin_amdgcn_mfma_f32_16x16x32_bf16(a0_, bq_, acc0, 0, 0, 0); \
        acc1 = __builtin_amdgcn_mfma_f32_16x16x32_bf16(a1_, bq_, acc1, 0, 0, 0); \
    } while (0)

// ---- prepass: regions fp32 -> bf16 fragments in exact LDS image order ----
__global__ __launch_bounds__(512)
void region_prepass(const float* __restrict__ in0, bf16x8* __restrict__ wsb) {
    const int gid = blockIdx.x * 512 + threadIdx.x;    // 0 .. 64*5120-1
    const int b = gid / FRAGS;
    const int S = gid - b * FRAGS;
    const float* reg0 = in0 + (size_t)b * NREG * DDIM;
    const float* src;
    if (S < KSTEPS * 64) {                 // lds0 image: rows 0-15
        const int ks = S >> 6, l = S & 63, r = l & 15, g = l >> 4;
        src = reg0 + (size_t)r * DDIM + ks * 32 + g * 8;
    } else {                               // lds1 image: rows 16-19 compact
        const int s = S - KSTEPS * 64;
        const int ks = s >> 4, r4 = (s >> 2) & 3, g = s & 3;
        src = reg0 + (size_t)(16 + r4) * DDIM + ks * 32 + g * 8;
    }
    const f32x4 x = *reinterpret_cast<const f32x4*>(src);
    const f32x4 y = *reinterpret_cast<const f32x4*>(src + 4);
    bf16x8 o; CVT8(o, x, y);
    wsb[gid] = o;
}

// ---- main kernel: stage bf16 fragments via async global_load_lds ----
__global__ __launch_bounds__(TPB)
void score_mfma2(const bf16x8* __restrict__ wsb,    // (64, 5120) fragments
                 const float* __restrict__ in1,     // (B, L, D) words
                 float* __restrict__ out) {         // (B, 1, L)
    __shared__ bf16x8 ldsA[FRAGS];                  // 80 KB: lds0 | lds1
    bf16x8* lds0 = ldsA;
    bf16x8* lds1 = ldsA + KSTEPS * 64;

    const int bid  = blockIdx.x;
    const int b    = bid & 63;              // batch -> XCD b%8
    const int tb   = bid >> 6;              // word slab 0..7 (128 words each)
    const int tid  = threadIdx.x;
    const int wave = tid >> 6;
    const int lane = tid & 63;
    const int col  = lane & 15;
    const int kg   = lane >> 4;

    const float* wbase = in1
        + ((size_t)b * LWORDS + tb * 128 + wave * 16 + col) * DDIM + kg * 8;
    const char* wsb_b = reinterpret_cast<const char*>(wsb + (size_t)b * FRAGS);

    // pre-issue first word loads (oldest in vmcnt queue; complete at barrier)
    f32x4 pa0, pa1, pb0, pb1;
    WLOAD(pa0, pa1, 0);
    WLOAD(pb0, pb1, 1);

    // stage 80 KB as 80 x 1KB tiles, 10 per wave, fully async
    #pragma unroll
    for (int i = 0; i < 10; ++i) {
        const int t = i * 8 + wave;          // wave-uniform tile id 0..79
        gload_lds16(wsb_b + (size_t)t * 1024 + lane * 16, &ldsA[t * 64]);
    }
    __syncthreads();   // drains gload_lds + word prefetches; ONLY barrier

    f32x4 acc0 = {0.f, 0.f, 0.f, 0.f};      // rows 0-15
    f32x4 acc1 = {0.f, 0.f, 0.f, 0.f};      // rows 16-19 (x4 duplicated)

    for (int ks = 0; ks < KSTEPS - 2; ks += 2) {
        CSTEP(ks,     pa0, pa1);  WLOAD(pa0, pa1, ks + 2);
        CSTEP(ks + 1, pb0, pb1);  WLOAD(pb0, pb1, ks + 3);
    }
    CSTEP(KSTEPS - 2, pa0, pa1);            // peeled tail: no loads, no guards
    CSTEP(KSTEPS - 1, pb0, pb1);

    // D layout (m89-verified): col = lane&15, row = (lane>>4)*4 + reg.
    float m = fmaxf(fmaxf(fmaxf(acc0[0], acc0[1]), fmaxf(acc0[2], acc0[3])),
                    fmaxf(fmaxf(acc1[0], acc1[1]), fmaxf(acc1[2], acc1[3])));
    m = fmaxf(m, __shfl_xor(m, 16, 64));
    m = fmaxf(m, __shfl_xor(m, 32, 64));
    if (lane < 16)
        out[(size_t)b * LWORDS + tb * 128 + wave * 16 + col] = m;
}

// ---- fallback (ws too small): round-15 kernel, fp32 staging in-kernel ----
__global__ __launch_bounds__(TPB)
void score_mfma_kernel(const float* __restrict__ in0,
                       const float* __restrict__ in1,
                       float* __restrict__ out) {
    __shared__ bf16x8 lds0[KSTEPS * 64];
    __shared__ bf16x8 lds1[KSTEPS * 16];

    const int bid  = blockIdx.x;
    const int b    = bid & 63;
    const int tb   = bid >> 6;
    const int tid  = threadIdx.x;
    const int wave = tid >> 6;
    const int lane = tid & 63;
    const int col  = lane & 15;
    const int kg   = lane >> 4;

    const float* reg0 = in0 + (size_t)b * NREG * DDIM;
    const float* wbase = in1
        + ((size_t)b * LWORDS + tb * 128 + wave * 16 + col) * DDIM + kg * 8;

    f32x4 pa0, pa1, pb0, pb1;
    WLOAD(pa0, pa1, 0);
    WLOAD(pb0, pb1, 1);

    #pragma unroll
    for (int i = 0; i < 8; ++i) {
        const int S = i * TPB + tid;
        const int ks = S >> 6, l = S & 63, r = l & 15, g = l >> 4;
        const float* src = reg0 + (size_t)r * DDIM + ks * 32 + g * 8;
        const f32x4 x = *reinterpret_cast<const f32x4*>(src);
        const f32x4 y = *reinterpret_cast<const f32x4*>(src + 4);
        bf16x8 o; CVT8(o, x, y);
        lds0[S] = o;
    }
    #pragma unroll
    for (int i = 0; i < 2; ++i) {
        const int S = i * TPB + tid;
        const int ks = S >> 4, r4 = (S >> 2) & 3, g = S & 3;
        const float* src = reg0 + (size_t)(16 + r4) * DDIM + ks * 32 + g * 8;
        const f32x4 x = *reinterpret_cast<const f32x4*>(src);
        const f32x4 y = *reinterpret_cast<const f32x4*>(src + 4);
        bf16x8 o; CVT8(o, x, y);
        lds1[S] = o;
    }
    __syncthreads();

    f32x4 acc0 = {0.f, 0.f, 0.f, 0.f};
    f32x4 acc1 = {0.f, 0.f, 0.f, 0.f};

    for (int ks = 0; ks < KSTEPS - 2; ks += 2) {
        CSTEP(ks,     pa0, pa1);  WLOAD(pa0, pa1, ks + 2);
        CSTEP(ks + 1, pb0, pb1);  WLOAD(pb0, pb1, ks + 3);
    }
    CSTEP(KSTEPS - 2, pa0, pa1);
    CSTEP(KSTEPS - 1, pb0, pb1);

    float m = fmaxf(fmaxf(fmaxf(acc0[0], acc0[1]), fmaxf(acc0[2], acc0[3])),
                    fmaxf(fmaxf(acc1[0], acc1[1]), fmaxf(acc1[2], acc1[3])));
    m = fmaxf(m, __shfl_xor(m, 16, 64));
    m = fmaxf(m, __shfl_xor(m, 32, 64));
    if (lane < 16)
        out[(size_t)b * LWORDS + tb * 128 + wave * 16 + col] = m;
}

extern "C" void kernel_launch(void* const* d_in, const int* in_sizes, int n_in,
                              void* d_out, int out_size, void* d_ws, size_t ws_size,
                              hipStream_t stream) {
    const float* in0 = (const float*)d_in[0];   // (B*20, D)
    const float* in1 = (const float*)d_in[1];   // (B, L, D)
    float* out = (float*)d_out;                  // (B, 1, L)

    const size_t ws_need = (size_t)64 * FRAGS * 16;   // 5.24 MB
    const int grid = 64 * (LWORDS / 128);             // 512 blocks

    if (ws_size >= ws_need) {
        bf16x8* wsb = (bf16x8*)d_ws;
        region_prepass<<<(64 * FRAGS) / 512, 512, 0, stream>>>(in0, wsb);
        score_mfma2<<<grid, TPB, 0, stream>>>(wsb, in1, out);
    } else {
        score_mfma_kernel<<<grid, TPB, 0, stream>>>(in0, in1, out);
    }
}

// Round 19
// 110.598 us; speedup vs baseline: 1.0599x; 1.0145x over previous
//
#include <hip/hip_runtime.h>
#include <hip/hip_bf16.h>
#include <math.h>
#include <string.h>

// Problem: B=64, R=20, L=1024, D=2048 fp32.  out[b,l] = max_r <region[b,r,:], word[b,l,:]>
// Memory-bound: 548 MB mandatory.  Best measured: this kernel, 110.7us
// (round 15) ~= 5.0-5.6 TB/s effective vs 6.3-6.6 TB/s device ceiling.
//
// Final structure (rounds 11-18 convergence):
//  - MFMA 16x16x32 bf16: acc = 8 VGPR (fp32-scalar version's 80-VGPR acc
//    forced a barrier-phased pipeline that plateaued at 144us).
//  - regions staged ONCE per block as bf16 A-fragments in 80 KB LDS
//    (ONE barrier in the whole kernel); M=20 = rows 0-15 tile + rows 16-19
//    replicated 4x (duplicates harmless under max; zero-pad would not be).
//  - words streamed from global in named-reg 2-deep ping-pong (deeper
//    crosses the 128-VGPR occupancy cliff: rounds 6/9/12 all -2x).
//  - fp32->bf16 via v_cvt_pk_bf16_f32 (__float22bfloat162_rn), -3.5us.
//  - falsified: NT loads (+6us), region prepass (+1.5us), K-split 2x
//    occupancy (+5us), restage-reduction blocks (+127us), vmcnt reorder (0).
#define NREG   20
#define LWORDS 1024
#define DDIM   2048
#define TPB    512
#define KSTEPS (DDIM / 32)          // 64 MFMA K-steps

typedef __attribute__((ext_vector_type(8))) short bf16x8;
typedef __attribute__((ext_vector_type(4))) float f32x4;
typedef __attribute__((ext_vector_type(4))) unsigned int u32x4;

// pack 2 fp32 -> 2 bf16 (RNE) -> one u32; compiler emits v_cvt_pk_bf16_f32
__device__ __forceinline__ unsigned pk2(float lo, float hi) {
    __hip_bfloat162 h = __float22bfloat162_rn(make_float2(lo, hi));
    unsigned u;
    memcpy(&u, &h, 4);
    return u;
}

// p0,p1 are f32x4 (ext-vector, [] indexed)
#define CVT8(bq, p0, p1)                                                       \
    do {                                                                       \
        u32x4 t_;                                                              \
        t_[0] = pk2(p0[0], p0[1]); t_[1] = pk2(p0[2], p0[3]);                  \
        t_[2] = pk2(p1[0], p1[1]); t_[3] = pk2(p1[2], p1[3]);                  \
        memcpy(&bq, &t_, 16);                                                  \
    } while (0)

// unguarded: callers guarantee kk < KSTEPS
#define WLOAD(va, vb, kk)                                                      \
    do {                                                                       \
        const f32x4* p_ = reinterpret_cast<const f32x4*>(                      \
            wbase + (size_t)(kk) * 32);                                        \
        va = *p_;                                                              \
        vb = *(p_ + 1);                                                        \
    } while (0)

// one MFMA K-step: cvt word regs -> bf16, read A-fragments, 2 MFMAs
#define CSTEP(kk, va, vb)                                                      \
    do {                                                                       \
        bf16x8 bq_; CVT8(bq_, va, vb);                                         \
        const bf16x8 a0_ = lds0[(kk) * 64 + lane];                             \
        const bf16x8 a1_ = lds1[(kk) * 16 + (col & 3) * 4 + kg];               \
        acc0 = __builtin_amdgcn_mfma_f32_16x16x32_bf16(a0_, bq_, acc0, 0, 0, 0); \
        acc1 = __builtin_amdgcn_mfma_f32_16x16x32_bf16(a1_, bq_, acc1, 0, 0, 0); \
    } while (0)

__global__ __launch_bounds__(TPB)
void score_mfma_kernel(const float* __restrict__ in0,   // (B*20, D) regions
                       const float* __restrict__ in1,   // (B, L, D) words
                       float* __restrict__ out) {       // (B, 1, L)
    // A-fragments, lane-sequential 16B reads (conflict-free):
    //  lds0[ks*64 + lane]          : rows 0-15,  row=lane&15, k=ks*32+(lane>>4)*8
    //  lds1[ks*16 + (row&3)*4 + kg]: rows 16-19 compact (4-lane broadcast read)
    __shared__ bf16x8 lds0[KSTEPS * 64];   // 64 KB
    __shared__ bf16x8 lds1[KSTEPS * 16];   // 16 KB

    const int bid  = blockIdx.x;
    const int b    = bid & 63;              // batch -> XCD b%8
    const int tb   = bid >> 6;              // word slab 0..7 (128 words each)
    const int tid  = threadIdx.x;
    const int wave = tid >> 6;
    const int lane = tid & 63;
    const int col  = lane & 15;             // word column within 16-word tile
    const int kg   = lane >> 4;             // k-group 0..3 (8 k each)

    const float* reg0 = in0 + (size_t)b * NREG * DDIM;
    const float* wbase = in1
        + ((size_t)b * LWORDS + tb * 128 + wave * 16 + col) * DDIM + kg * 8;

    // pre-issue the first two word prefetches: word stream starts at t=0,
    // overlapping the staging phase below.
    f32x4 pa0, pa1, pb0, pb1;
    WLOAD(pa0, pa1, 0);
    WLOAD(pb0, pb1, 1);

    // ---- stage regions once: fp32 -> bf16 -> fragment-ordered LDS ----
    #pragma unroll
    for (int i = 0; i < 8; ++i) {           // rows 0-15: 4096 slots
        const int S = i * TPB + tid;
        const int ks = S >> 6, l = S & 63, r = l & 15, g = l >> 4;
        const float* src = reg0 + (size_t)r * DDIM + ks * 32 + g * 8;
        const f32x4 x = *reinterpret_cast<const f32x4*>(src);
        const f32x4 y = *reinterpret_cast<const f32x4*>(src + 4);
        bf16x8 o; CVT8(o, x, y);
        lds0[S] = o;
    }
    #pragma unroll
    for (int i = 0; i < 2; ++i) {           // rows 16-19: 1024 slots
        const int S = i * TPB + tid;
        const int ks = S >> 4, r4 = (S >> 2) & 3, g = S & 3;
        const float* src = reg0 + (size_t)(16 + r4) * DDIM + ks * 32 + g * 8;
        const f32x4 x = *reinterpret_cast<const f32x4*>(src);
        const f32x4 y = *reinterpret_cast<const f32x4*>(src + 4);
        bf16x8 o; CVT8(o, x, y);
        lds1[S] = o;
    }
    __syncthreads();   // the ONLY barrier in the kernel

    f32x4 acc0 = {0.f, 0.f, 0.f, 0.f};      // rows 0-15
    f32x4 acc1 = {0.f, 0.f, 0.f, 0.f};      // rows 16-19 (x4 duplicated)

    for (int ks = 0; ks < KSTEPS - 2; ks += 2) {
        CSTEP(ks,     pa0, pa1);  WLOAD(pa0, pa1, ks + 2);
        CSTEP(ks + 1, pb0, pb1);  WLOAD(pb0, pb1, ks + 3);
    }
    CSTEP(KSTEPS - 2, pa0, pa1);            // peeled tail: no loads, no guards
    CSTEP(KSTEPS - 1, pb0, pb1);

    // ---- max over regions ----
    // D layout (m89-verified): col = lane&15, row = (lane>>4)*4 + reg.
    float m = fmaxf(fmaxf(fmaxf(acc0[0], acc0[1]), fmaxf(acc0[2], acc0[3])),
                    fmaxf(fmaxf(acc1[0], acc1[1]), fmaxf(acc1[2], acc1[3])));
    m = fmaxf(m, __shfl_xor(m, 16, 64));
    m = fmaxf(m, __shfl_xor(m, 32, 64));
    if (lane < 16)
        out[(size_t)b * LWORDS + tb * 128 + wave * 16 + col] = m;
}

extern "C" void kernel_launch(void* const* d_in, const int* in_sizes, int n_in,
                              void* d_out, int out_size, void* d_ws, size_t ws_size,
                              hipStream_t stream) {
    const float* in0 = (const float*)d_in[0];   // (B*20, D)
    const float* in1 = (const float*)d_in[1];   // (B, L, D)
    float* out = (float*)d_out;                  // (B, 1, L)

    const int grid = 64 * (LWORDS / 128);        // 512 blocks, 2/CU (80KB LDS)
    score_mfma_kernel<<<grid, TPB, 0, stream>>>(in0, in1, out);
}